// Round 1
// baseline (166.168 us; speedup 1.0000x reference)
//
#include <hip/hip_runtime.h>

// Problem constants
// B=16, C=256, O=256, H=W=64, T_DIM=512, E=4, K=3

typedef __bf16 bf16x8 __attribute__((ext_vector_type(8)));
typedef float f32x4 __attribute__((ext_vector_type(4)));

__device__ __forceinline__ unsigned short f2bf(float f) {
  union { float f; unsigned int u; } v;
  v.f = f;
  unsigned int r = v.u + 0x7FFFu + ((v.u >> 16) & 1u);  // RNE
  return (unsigned short)(r >> 16);
}

__device__ __forceinline__ void load_lds16(const void* g, void* l) {
  __builtin_amdgcn_global_load_lds(
      (__attribute__((address_space(1))) void*)(void*)g,
      (__attribute__((address_space(3))) void*)l, 16, 0, 0);
}

// ---------------- pooling: pooled[b*256+c] = mean over H*W ----------------
__global__ void pool_kernel(const float* __restrict__ x, float* __restrict__ pooled) {
  int bc = blockIdx.x;                       // b*256 + c
  const float* p = x + (size_t)bc * 4096;
  int t = threadIdx.x;
  float s = 0.f;
  for (int i = t; i < 4096; i += 256) s += p[i];
  __shared__ float red[4];
  #pragma unroll
  for (int off = 32; off > 0; off >>= 1) s += __shfl_down(s, off);
  if ((t & 63) == 0) red[t >> 6] = s;
  __syncthreads();
  if (t == 0) pooled[bc] = (red[0] + red[1] + red[2] + red[3]) * (1.0f / 4096.0f);
}

// ---------------- transpose x[b][c][h][w] fp32 -> xT[b][h][w][c] bf16 ----------------
__global__ void transpose_kernel(const float* __restrict__ x, unsigned short* __restrict__ xT) {
  int bh = blockIdx.x;          // b*64 + h
  int b = bh >> 6, h = bh & 63;
  __shared__ unsigned short lds[256][68];    // +4 pad: 2-way (free) bank pattern on read
  int t = threadIdx.x;
  int w = t & 63, cg = t >> 6;
  for (int it = 0; it < 64; ++it) {
    int c = it * 4 + cg;
    float v = x[(((size_t)(b * 256 + c)) * 64 + h) * 64 + w];
    lds[c][w] = f2bf(v);
  }
  __syncthreads();
  size_t obase = (size_t)bh * 64 * 256;
  for (int ww = 0; ww < 64; ++ww) {
    xT[obase + (size_t)ww * 256 + t] = lds[t][ww];
  }
}

// ---------------- router (fp32 exact), writes rw[16][4] and beff[16][256] ----------------
__global__ void router_kernel(
    const float* __restrict__ time_emb, const float* __restrict__ pooled,
    const float* __restrict__ Wq, const float* __restrict__ bq,
    const float* __restrict__ Wk, const float* __restrict__ bk,
    const float* __restrict__ Wv, const float* __restrict__ bv,
    const float* __restrict__ Wm1, const float* __restrict__ bm1,
    const float* __restrict__ Wm2, const float* __restrict__ bm2,
    const float* __restrict__ Wc, const float* __restrict__ bc,
    const float* __restrict__ expert_b,
    float* __restrict__ rw_out, float* __restrict__ beff_out) {
  int b = blockIdx.x, t = threadIdx.x;
  __shared__ float te[512], pl[256], xa[256], m1s[64], xms[256], rws[4];
  te[t] = time_emb[b * 512 + t];
  te[t + 256] = time_emb[b * 512 + 256 + t];
  pl[t] = pooled[b * 256 + t];
  __syncthreads();
  float q = bq[t], k = bk[t], v = bv[t];
  const float* wq = Wq + (size_t)t * 512;
  for (int i = 0; i < 512; ++i) q += te[i] * wq[i];
  const float* wk = Wk + (size_t)t * 256;
  const float* wv = Wv + (size_t)t * 256;
  for (int i = 0; i < 256; ++i) { float p = pl[i]; k += p * wk[i]; v += p * wv[i]; }
  float attn = 1.0f / (1.0f + expf(-(q * k)));
  float xatt = v * attn;
  xa[t] = xatt;
  __syncthreads();
  if (t < 64) {
    float s = bm1[t];
    const float* w1 = Wm1 + (size_t)t * 256;
    for (int i = 0; i < 256; ++i) s += xa[i] * w1[i];
    m1s[t] = 0.5f * s * (1.0f + erff(s * 0.7071067811865476f));  // exact gelu
  }
  __syncthreads();
  float hsum = bm2[t];
  const float* w2 = Wm2 + (size_t)t * 64;
  for (int j = 0; j < 64; ++j) hsum += m1s[j] * w2[j];
  float xm = xatt + hsum;
  xms[t] = xm;
  __syncthreads();
  if (t < 4) {
    float s = bc[t];
    const float* wc = Wc + (size_t)t * 256;
    for (int i = 0; i < 256; ++i) s += xms[i] * wc[i];
    float r = tanhf(s);
    rws[t] = r;
    rw_out[b * 4 + t] = r;
  }
  __syncthreads();
  float be = 0.f;
  #pragma unroll
  for (int e = 0; e < 4; ++e) be += rws[e] * expert_b[e * 256 + t];
  beff_out[b * 256 + t] = be;
}

// ---------------- expert mix: wmix[b][o][tap][c] bf16 = sum_e rw[b][e]*expert_w[e][o][c][kh][kw]
__global__ void wmix_kernel(const float* __restrict__ ew, const float* __restrict__ rw,
                            unsigned short* __restrict__ wmix) {
  int o = blockIdx.x & 255;
  int b0 = (blockIdx.x >> 8) << 2;   // 4 samples per block
  int c = threadIdx.x;
  float wv[4][9];
  #pragma unroll
  for (int e = 0; e < 4; ++e) {
    const float* s = ew + (((size_t)e * 256 + o) * 256 + c) * 9;
    #pragma unroll
    for (int tt = 0; tt < 9; ++tt) wv[e][tt] = s[tt];
  }
  for (int b = b0; b < b0 + 4; ++b) {
    float r0 = rw[b * 4 + 0], r1 = rw[b * 4 + 1], r2 = rw[b * 4 + 2], r3 = rw[b * 4 + 3];
    #pragma unroll
    for (int tt = 0; tt < 9; ++tt) {
      float m = r0 * wv[0][tt] + r1 * wv[1][tt] + r2 * wv[2][tt] + r3 * wv[3][tt];
      wmix[(((size_t)(b * 256 + o)) * 9 + tt) * 256 + c] = f2bf(m);
    }
  }
}

// ---------------- conv as implicit GEMM (per-sample), MFMA bf16 ----------------
// grid = 16b * 2ot * 32ht = 1024 blocks, 256 threads (4 waves, 2x2)
// A = wmix[b][o][tap][c] (M=128 rows of o, K-slice = 32 c of one tap)
// B = xT staged into zero-padded LDS [4 rows][66 cols][32 c]
__global__ __launch_bounds__(256, 2) void conv_kernel(
    const unsigned short* __restrict__ xT, const unsigned short* __restrict__ wmix,
    const float* __restrict__ beff, float* __restrict__ out) {
  __shared__ unsigned short As[128 * 32];        // 8 KB
  __shared__ unsigned short Bs[4 * 66 * 32];     // 16.5 KB
  int bid = blockIdx.x;
  int b = bid >> 6;
  int rem = bid & 63;
  int o0 = (rem >> 5) << 7;     // 0 or 128
  int h0 = (rem & 31) << 1;     // 0..62 step 2
  int tid = threadIdx.x;
  int wid = tid >> 6, lane = tid & 63;
  int lm = lane & 15, lg = lane >> 4;
  int wm = wid >> 1, wn = wid & 1;

  // zero halo columns (w=-1 and w=64) once; never overwritten by staging
  if (tid < 128) {
    int rr = tid >> 5, colw = ((tid >> 4) & 1) ? 65 : 0, cp = tid & 15;
    *(unsigned int*)&Bs[(rr * 66 + colw) * 32 + cp * 2] = 0u;
  }

  f32x4 acc[4][4];
  #pragma unroll
  for (int mf = 0; mf < 4; ++mf)
    #pragma unroll
    for (int nf = 0; nf < 4; ++nf)
      acc[mf][nf] = (f32x4){0.f, 0.f, 0.f, 0.f};

  int aoff[4];
  #pragma unroll
  for (int mf = 0; mf < 4; ++mf)
    aoff[mf] = (wm * 64 + mf * 16 + lm) * 32 + lg * 8;
  int bbase[4];
  #pragma unroll
  for (int nf = 0; nf < 4; ++nf) {
    int p = wn * 64 + nf * 16 + lm;
    int hr = p >> 6, w = p & 63;
    bbase[nf] = (hr * 66 + w) * 32 + lg * 8;
  }

  const unsigned short* xTb = xT + (size_t)b * 4096 * 256;
  const unsigned short* wmb = wmix + ((size_t)b * 256 + o0) * 9 * 256;

  for (int cc = 0; cc < 8; ++cc) {
    int c0 = cc * 32;
    // ---- stage B: wave wid handles LDS row wid (global h = h0-1+wid) ----
    {
      int r = wid;
      int hh = h0 - 1 + r;
      unsigned short* dst = &Bs[(r * 66 + 1) * 32];
      if (hh >= 0 && hh < 64) {
        const unsigned short* src = xTb + (size_t)hh * 64 * 256 + c0;
        #pragma unroll
        for (int qq = 0; qq < 4; ++qq) {
          int wq = qq * 16 + (lane >> 2);
          int slot = lane & 3;
          load_lds16(src + (size_t)wq * 256 + slot * 8, dst + qq * 512);
        }
      } else {
        #pragma unroll
        for (int qq = 0; qq < 4; ++qq) {
          *(uint4*)&dst[qq * 512 + lane * 8] = make_uint4(0u, 0u, 0u, 0u);
        }
      }
    }
    // ---- 9 taps share the staged B chunk ----
    #pragma unroll
    for (int tap = 0; tap < 9; ++tap) {
      // stage A tile [128 o][32 c] for this (tap, c-chunk)
      {
        const unsigned short* asrc = wmb + (size_t)tap * 256 + c0;
        #pragma unroll
        for (int qq = 0; qq < 2; ++qq) {
          int row = wid * 32 + qq * 16 + (lane >> 2);
          int slot = lane & 3;
          load_lds16(asrc + (size_t)row * (9 * 256) + slot * 8,
                     &As[(wid * 32 + qq * 16) * 32]);
        }
      }
      __syncthreads();   // drains vmcnt(0): A and (first tap) B staging complete
      int kh = tap / 3, kw = tap % 3;
      int tshift = (kh * 66 + kw) * 32;
      bf16x8 af[4], bfr[4];
      #pragma unroll
      for (int mf = 0; mf < 4; ++mf) af[mf] = *(const bf16x8*)&As[aoff[mf]];
      #pragma unroll
      for (int nf = 0; nf < 4; ++nf) bfr[nf] = *(const bf16x8*)&Bs[bbase[nf] + tshift];
      #pragma unroll
      for (int mf = 0; mf < 4; ++mf)
        #pragma unroll
        for (int nf = 0; nf < 4; ++nf)
          acc[mf][nf] = __builtin_amdgcn_mfma_f32_16x16x32_bf16(af[mf], bfr[nf], acc[mf][nf], 0, 0, 0);
      __syncthreads();   // protect As (and Bs at chunk boundary) before restage
    }
  }

  // ---- epilogue: C/D layout col=lane&15, row=(lane>>4)*4+reg ----
  float be[4][4];
  #pragma unroll
  for (int mf = 0; mf < 4; ++mf)
    #pragma unroll
    for (int r = 0; r < 4; ++r)
      be[mf][r] = beff[b * 256 + o0 + wm * 64 + mf * 16 + lg * 4 + r];
  #pragma unroll
  for (int mf = 0; mf < 4; ++mf) {
    int o = o0 + wm * 64 + mf * 16 + lg * 4;
    #pragma unroll
    for (int nf = 0; nf < 4; ++nf) {
      int p = wn * 64 + nf * 16 + lm;
      int h = h0 + (p >> 6), w = p & 63;
      float* op = out + (((size_t)(b * 256 + o)) * 64 + h) * 64 + w;
      #pragma unroll
      for (int r = 0; r < 4; ++r) {
        op[(size_t)r * 4096] = acc[mf][nf][r] + be[mf][r];
      }
    }
  }
}

extern "C" void kernel_launch(void* const* d_in, const int* in_sizes, int n_in,
                              void* d_out, int out_size, void* d_ws, size_t ws_size,
                              hipStream_t stream) {
  const float* x        = (const float*)d_in[0];
  const float* time_emb = (const float*)d_in[1];
  const float* Wq = (const float*)d_in[2];
  const float* bq = (const float*)d_in[3];
  const float* Wk = (const float*)d_in[4];
  const float* bk = (const float*)d_in[5];
  const float* Wv = (const float*)d_in[6];
  const float* bv = (const float*)d_in[7];
  const float* Wm1 = (const float*)d_in[8];
  const float* bm1 = (const float*)d_in[9];
  const float* Wm2 = (const float*)d_in[10];
  const float* bm2 = (const float*)d_in[11];
  const float* Wc = (const float*)d_in[12];
  const float* bc = (const float*)d_in[13];
  const float* expert_w = (const float*)d_in[14];
  const float* expert_b = (const float*)d_in[15];
  float* out = (float*)d_out;

  char* ws = (char*)d_ws;
  float* pooled = (float*)(ws + 0);                       // 16 KB
  float* rw     = (float*)(ws + 16384);                   // 256 B
  float* beff   = (float*)(ws + 16384 + 1024);            // 16 KB
  unsigned short* xT   = (unsigned short*)(ws + 65536);               // 32 MB
  unsigned short* wmix = (unsigned short*)(ws + 65536 + 33554432);    // 18.9 MB

  pool_kernel<<<4096, 256, 0, stream>>>(x, pooled);
  transpose_kernel<<<1024, 256, 0, stream>>>(x, xT);
  router_kernel<<<16, 256, 0, stream>>>(time_emb, pooled, Wq, bq, Wk, bk, Wv, bv,
                                        Wm1, bm1, Wm2, bm2, Wc, bc, expert_b, rw, beff);
  wmix_kernel<<<1024, 256, 0, stream>>>(expert_w, rw, wmix);
  conv_kernel<<<1024, 256, 0, stream>>>(xT, wmix, beff, out);
}